// Round 1
// baseline (194.556 us; speedup 1.0000x reference)
//
#include <hip/hip_runtime.h>

// Cosine-similarity attention context:
//   dots[s]  = keys[s,:] . q
//   cos[s]   = dots[s] / (||q|| * ||keys[s,:]||)
//   ctx[h]   = sum_s cos[s] * keys[s,h]
// keys = 32768 x 1024 f32 (128 MiB) -> HBM-bound, single pass over keys.

constexpr int H   = 1024;   // hidden dim (fixed by problem)
constexpr int TPB = 256;    // 4 waves per block
constexpr int WPB = TPB / 64;
constexpr int NBLOCKS = 512;      // 2048 waves total = 8 waves/CU
constexpr int R2_CHUNKS = 16;     // reduce-kernel parallelism over block-partials

// One row per wave: lane holds columns {j*256 + 4*lane + k}, j=0..3, k=0..3
// (four fully-coalesced float4 loads per row).

template <bool USE_WS>
__global__ __launch_bounds__(TPB, 2)
void cosctx_main(const float* __restrict__ q,
                 const float* __restrict__ keys,
                 int S,
                 float* __restrict__ out,
                 float* __restrict__ ws)
{
    const int lane  = threadIdx.x & 63;
    const int wave  = threadIdx.x >> 6;
    const int gwave = blockIdx.x * WPB + wave;
    const int nwaves = gridDim.x * WPB;

    const float4* q4 = reinterpret_cast<const float4*>(q);
    const float4* k4 = reinterpret_cast<const float4*>(keys);

    // --- query fragment + 1/||q|| (redundant per wave; q is 4 KiB, L2-hot) ---
    float4 qv[4];
#pragma unroll
    for (int j = 0; j < 4; ++j) qv[j] = q4[j * 64 + lane];

    float qsq = 0.f;
#pragma unroll
    for (int j = 0; j < 4; ++j)
        qsq += qv[j].x * qv[j].x + qv[j].y * qv[j].y +
               qv[j].z * qv[j].z + qv[j].w * qv[j].w;
#pragma unroll
    for (int off = 32; off > 0; off >>= 1) qsq += __shfl_down(qsq, off, 64);
    const float inv_qn = rsqrtf(__shfl(qsq, 0, 64));

    float4 acc[4];
#pragma unroll
    for (int j = 0; j < 4; ++j) acc[j] = make_float4(0.f, 0.f, 0.f, 0.f);

    // --- single pass over rows, 1-row prefetch pipeline ---
    int row = gwave;
    float4 kv[4];
    if (row < S) {
        const float4* kr = k4 + (size_t)row * (H / 4);
#pragma unroll
        for (int j = 0; j < 4; ++j) kv[j] = kr[j * 64 + lane];
    }
    while (row < S) {
        const int nrow = row + nwaves;
        float4 kn[4];
        if (nrow < S) {
            const float4* kr = k4 + (size_t)nrow * (H / 4);
#pragma unroll
            for (int j = 0; j < 4; ++j) kn[j] = kr[j * 64 + lane];
        }

        float dot = 0.f, ksq = 0.f;
#pragma unroll
        for (int j = 0; j < 4; ++j) {
            dot += kv[j].x * qv[j].x + kv[j].y * qv[j].y +
                   kv[j].z * qv[j].z + kv[j].w * qv[j].w;
            ksq += kv[j].x * kv[j].x + kv[j].y * kv[j].y +
                   kv[j].z * kv[j].z + kv[j].w * kv[j].w;
        }
        // two interleaved (independent) shuffle-reduce chains, no barriers
#pragma unroll
        for (int off = 32; off > 0; off >>= 1) {
            dot += __shfl_down(dot, off, 64);
            ksq += __shfl_down(ksq, off, 64);
        }
        const float score = __shfl(dot, 0, 64) * inv_qn *
                            rsqrtf(__shfl(ksq, 0, 64));

#pragma unroll
        for (int j = 0; j < 4; ++j) {
            acc[j].x += score * kv[j].x;
            acc[j].y += score * kv[j].y;
            acc[j].z += score * kv[j].z;
            acc[j].w += score * kv[j].w;
        }
#pragma unroll
        for (int j = 0; j < 4; ++j) kv[j] = kn[j];
        row = nrow;
    }

    // --- block reduce: 4 wave-partials -> 1 block-partial [H] ---
    __shared__ float sacc[WPB][H];   // 16 KiB
    float4* sa4 = reinterpret_cast<float4*>(sacc[wave]);
#pragma unroll
    for (int j = 0; j < 4; ++j) sa4[j * 64 + lane] = acc[j];
    __syncthreads();

    float4 v = make_float4(0.f, 0.f, 0.f, 0.f);
#pragma unroll
    for (int w = 0; w < WPB; ++w) {
        float4 u = reinterpret_cast<const float4*>(sacc[w])[threadIdx.x];
        v.x += u.x; v.y += u.y; v.z += u.z; v.w += u.w;
    }

    if (USE_WS) {
        // block-partial to workspace, non-atomic; reduced by second kernel
        reinterpret_cast<float4*>(ws)[(size_t)blockIdx.x * (H / 4) + threadIdx.x] = v;
    } else {
        // fallback: device-scope atomics straight into out (out pre-zeroed)
        const int c = threadIdx.x * 4;
        atomicAdd(out + c + 0, v.x);
        atomicAdd(out + c + 1, v.y);
        atomicAdd(out + c + 2, v.z);
        atomicAdd(out + c + 3, v.w);
    }
}

// Reduce NBLOCKS x H block-partials (2 MiB, L2/L3-hot) into out.
// 64 blocks: 16 chunks over the block axis x 4 column groups; ~16 atomics/addr.
__global__ __launch_bounds__(256)
void cosctx_reduce(const float* __restrict__ ws, float* __restrict__ out)
{
    const int g  = blockIdx.x & 3;         // column group (256 cols each)
    const int ch = blockIdx.x >> 2;        // chunk of block-partials
    const int c  = g * 256 + threadIdx.x;
    const int bpc = NBLOCKS / R2_CHUNKS;   // 32
    const int b0 = ch * bpc;
    float s = 0.f;
#pragma unroll 4
    for (int b = b0; b < b0 + bpc; ++b)
        s += ws[(size_t)b * H + c];
    atomicAdd(out + c, s);
}

extern "C" void kernel_launch(void* const* d_in, const int* in_sizes, int n_in,
                              void* d_out, int out_size, void* d_ws, size_t ws_size,
                              hipStream_t stream)
{
    const float* q    = (const float*)d_in[0];
    const float* keys = (const float*)d_in[1];
    float* out        = (float*)d_out;
    const int S = in_sizes[1] / H;

    // d_out is poisoned 0xAA before every call; both paths accumulate into it.
    hipMemsetAsync(out, 0, H * sizeof(float), stream);

    const size_t ws_need = (size_t)NBLOCKS * H * sizeof(float);
    if (ws_size >= ws_need) {
        cosctx_main<true><<<NBLOCKS, TPB, 0, stream>>>(q, keys, S, out, (float*)d_ws);
        cosctx_reduce<<<4 * R2_CHUNKS, 256, 0, stream>>>((const float*)d_ws, out);
    } else {
        cosctx_main<false><<<NBLOCKS, TPB, 0, stream>>>(q, keys, S, out, nullptr);
    }
}